// Round 1
// baseline (11472.230 us; speedup 1.0000x reference)
//
#include <hip/hip_runtime.h>
#include <hip/hip_bf16.h>
#include <hip/hip_cooperative_groups.h>

#define H 1024
#define B3H 3072
#define BATCH 128
#define TSTEPS 256
#define LROW 520                 // 512 k-chunk + 8 pad (shorts)
#define PLANE (16 * LROW)        // one 16-row bf16 plane per chunk

typedef __attribute__((ext_vector_type(8))) short short8;
typedef __attribute__((ext_vector_type(4))) float f32x4;

static __device__ __forceinline__ float bf2f(__hip_bfloat16 v) { return __bfloat162float(v); }
static __device__ __forceinline__ unsigned short f2bf_bits(float f) {
    __hip_bfloat16 h = __float2bfloat16(f);
    return __builtin_bit_cast(unsigned short, h);
}
static __device__ __forceinline__ float bits2f(unsigned short b) {
    return bf2f(__builtin_bit_cast(__hip_bfloat16, b));
}
static __device__ __forceinline__ unsigned short bfbits(__hip_bfloat16 v) {
    return __builtin_bit_cast(unsigned short, v);
}
static __device__ __forceinline__ void split_bf(float v, unsigned short& hi, unsigned short& lo) {
    hi = f2bf_bits(v);
    lo = f2bf_bits(v - bits2f(hi));
}

// ws layout
#define PW_OFF   256
#define PWL_OFF  (PW_OFF + 12582912)
#define XHI_OFF  (PWL_OFF + 12582912)
#define XLO_OFF  (XHI_OFF + 262144)
#define H0HI_OFF (XLO_OFF + 262144)
#define H0LO_OFF (H0HI_OFF + 262144)
#define H1HI_OFF (H0LO_OFF + 262144)
#define H1LO_OFF (H1HI_OFF + 262144)

__global__ void detect_dtype(const unsigned int* __restrict__ w, int* __restrict__ flag) {
    __shared__ int cnt[256];
    int c = 0;
    for (int i = threadIdx.x; i < 4096; i += 256) {
        unsigned int v = (w[i] >> 8) & 0x7f;
        c += (v >= 0x33 && v <= 0x3f) ? 1 : 0;
    }
    cnt[threadIdx.x] = c;
    __syncthreads();
    for (int s = 128; s > 0; s >>= 1) {
        if (threadIdx.x < s) cnt[threadIdx.x] += cnt[threadIdx.x + s];
        __syncthreads();
    }
    if (threadIdx.x == 0) *flag = (cnt[0] * 2 > 4096) ? 1 : 0;
}

// Pack W into MFMA B-fragment layout, bf16 hi/lo pair (unchanged — verified).
__global__ void pack_w(const void* __restrict__ Kp, const void* __restrict__ Rp,
                       __hip_bfloat16* __restrict__ pwh, __hip_bfloat16* __restrict__ pwl,
                       const int* __restrict__ flag) {
    int idx = blockIdx.x * 256 + threadIdx.x;
    int lane = idx & 63;
    int kc   = (idx >> 6) & 31;
    int ns   = (idx >> 11) & 1;
    int it   = (idx >> 12) & 31;
    int g    = idx >> 17;
    if (g >= 6) return;
    const int isbf = *flag;
    int col   = (g % 3) * 1024 + it * 32 + ns * 16 + (lane & 15);
    int kbase = kc * 32 + (lane >> 4) * 8;
    unsigned short eh[8], el[8];
    if (isbf) {
        const __hip_bfloat16* src = (const __hip_bfloat16*)((g < 3) ? Kp : Rp);
#pragma unroll
        for (int j = 0; j < 8; ++j) { eh[j] = bfbits(src[(size_t)(kbase + j) * B3H + col]); el[j] = 0; }
    } else {
        const float* src = (const float*)((g < 3) ? Kp : Rp);
#pragma unroll
        for (int j = 0; j < 8; ++j) split_bf(src[(size_t)(kbase + j) * B3H + col], eh[j], el[j]);
    }
    uint4 vh, vl;
    vh.x = (unsigned int)eh[0] | ((unsigned int)eh[1] << 16);
    vh.y = (unsigned int)eh[2] | ((unsigned int)eh[3] << 16);
    vh.z = (unsigned int)eh[4] | ((unsigned int)eh[5] << 16);
    vh.w = (unsigned int)eh[6] | ((unsigned int)eh[7] << 16);
    vl.x = (unsigned int)el[0] | ((unsigned int)el[1] << 16);
    vl.y = (unsigned int)el[2] | ((unsigned int)el[3] << 16);
    vl.z = (unsigned int)el[4] | ((unsigned int)el[5] << 16);
    vl.w = (unsigned int)el[6] | ((unsigned int)el[7] << 16);
    *(uint4*)(pwh + (size_t)idx * 8) = vh;
    *(uint4*)(pwl + (size_t)idx * 8) = vl;
}

// Inputs -> pre-split bf16 hi/lo planes.
__global__ void init_bufs(const void* __restrict__ cin, const void* __restrict__ hs,
                          unsigned short* __restrict__ xhi, unsigned short* __restrict__ xlo,
                          unsigned short* __restrict__ hhi, unsigned short* __restrict__ hlo,
                          const int* __restrict__ flag) {
    int i = blockIdx.x * 256 + threadIdx.x;
    if (i >= BATCH * H) return;
    float xv, hv;
    if (*flag) {
        xv = bf2f(((const __hip_bfloat16*)cin)[i]);
        hv = bf2f(((const __hip_bfloat16*)hs)[i]);
    } else {
        xv = ((const float*)cin)[i];
        hv = ((const float*)hs)[i];
    }
    unsigned short a, b;
    split_bf(xv, a, b); xhi[i] = a; xlo[i] = b;
    split_bf(hv, a, b); hhi[i] = a; hlo[i] = b;
}

// ---------------------------------------------------------------------------
// Persistent GRU: all 256 timesteps in ONE cooperative kernel.
// Grid 256 WGs = 8 batch-tiles(16 rows) x 32 col-slices(32 cols), 384 threads
// = 6 gate-waves. Per-step GEMM/staging/epilogue identical to the verified
// per-launch version; steps separated by grid.sync() instead of kernel
// launches, so weights stay L2-hot and the per-launch dispatch+drain cost
// (≈10 µs/step) disappears. h_old kept in LDS (sHold, full f32); bias in LDS.
// ---------------------------------------------------------------------------
__launch_bounds__(384, 1)
__global__ void gru_persistent(const unsigned short* __restrict__ xhi,
                               const unsigned short* __restrict__ xlo,
                               unsigned short* __restrict__ h0hi,
                               unsigned short* __restrict__ h0lo,
                               unsigned short* __restrict__ h1hi,
                               unsigned short* __restrict__ h1lo,
                               const __hip_bfloat16* __restrict__ pwh,
                               const __hip_bfloat16* __restrict__ pwl,
                               const void* __restrict__ bias,
                               void* __restrict__ out,
                               const int* __restrict__ flag) {
    cooperative_groups::grid_group grid = cooperative_groups::this_grid();

    // planes: [0]=A_hi [1]=A_lo [2]=B_hi [3]=B_lo (2/3 only at t=0)
    __shared__ unsigned short sA[4 * PLANE];  // 66560 B (aliased as sG fp32 post-GEMM)
    __shared__ float sHold[512];              // this block's h tile, full f32
    __shared__ float sBias[192];              // 6 gates x 32 cols

    const int tid  = threadIdx.x;
    const int g    = tid >> 6;        // gate wave 0..5
    const int lane = tid & 63;
    const int bt = blockIdx.x >> 5;   // 0..7, 16-row tiles
    const int it = blockIdx.x & 31;   // 0..31, 32-col slices
    const int bbase = bt * 16;
    const int m0 = lane & 15;
    const int q  = lane >> 4;
    const int ibase0 = it * 32;
    const int isbf = *flag;

    // preload bias once
    {
        const __hip_bfloat16* bias_b = (const __hip_bfloat16*)bias;
        const float* bias_f = (const float*)bias;
        for (int e = tid; e < 192; e += 384) {
            int gg = e >> 5;
            int i  = ibase0 + (e & 31);
            int src = (gg < 3) ? (gg * 1024 + i) : (B3H + (gg - 3) * 1024 + i);
            sBias[e] = isbf ? bf2f(bias_b[src]) : bias_f[src];
        }
    }

    const size_t boff0 = ((size_t)((g * 32 + it) * 2 + 0) * 32) * 64 + lane;
    const size_t boff1 = ((size_t)((g * 32 + it) * 2 + 1) * 32) * 64 + lane;
    const uint4* bh0 = (const uint4*)pwh + boff0;
    const uint4* bh1 = (const uint4*)pwh + boff1;
    const uint4* bl0 = (const uint4*)pwl + boff0;
    const uint4* bl1 = (const uint4*)pwl + boff1;

    __hip_bfloat16* outb = (__hip_bfloat16*)out;
    float* outf = (float*)out;

    for (int t = 0; t < TSTEPS; ++t) {
        const int cur = t & 1;
        const unsigned short* curhi = cur ? h1hi : h0hi;
        const unsigned short* curlo = cur ? h1lo : h0lo;
        unsigned short* dsthi = cur ? h0hi : h1hi;
        unsigned short* dstlo = cur ? h0lo : h1lo;
        const unsigned short* aAhi = t ? curhi : xhi;   // gates 0-2 source
        const unsigned short* aAlo = t ? curlo : xlo;
        const int same_xh = (t != 0);
        const unsigned short* aH = sA + (((g < 3) || same_xh) ? 0 : 2) * PLANE;
        const unsigned short* aL = aH + PLANE;
        const int nGr = (same_xh ? 2 : 4) * 1024;

        f32x4 acc0 = {0.f, 0.f, 0.f, 0.f};
        f32x4 acc1 = {0.f, 0.f, 0.f, 0.f};

        for (int c = 0; c < 2; ++c) {     // two 512-k chunks
            if (c) __syncthreads();
            const int kstart = c * 512;
            for (int g4 = tid; g4 < nGr; g4 += 384) {
                int plane = g4 >> 10;
                int rem   = g4 & 1023;
                int row   = rem >> 6;
                int kg    = rem & 63;
                const unsigned short* src =
                    (plane == 0) ? aAhi : (plane == 1) ? aAlo : (plane == 2) ? curhi : curlo;
                uint4 v = *(const uint4*)&src[(size_t)(bbase + row) * H + kstart + kg * 8];
                *(uint4*)&sA[plane * PLANE + row * LROW + kg * 8] = v;
            }
            __syncthreads();
#pragma unroll 4
            for (int kc = 0; kc < 16; ++kc) {
                const int kcg = c * 16 + kc;
                short8 b0h = __builtin_bit_cast(short8, bh0[(size_t)kcg * 64]);
                short8 b1h = __builtin_bit_cast(short8, bh1[(size_t)kcg * 64]);
                short8 b0l = __builtin_bit_cast(short8, bl0[(size_t)kcg * 64]);
                short8 b1l = __builtin_bit_cast(short8, bl1[(size_t)kcg * 64]);
                const int koff = kc * 32 + q * 8;
                short8 a_h = *(const short8*)&aH[m0 * LROW + koff];
                short8 a_l = *(const short8*)&aL[m0 * LROW + koff];
                acc0 = __builtin_amdgcn_mfma_f32_16x16x32_bf16(a_h, b0h, acc0, 0, 0, 0);
                acc1 = __builtin_amdgcn_mfma_f32_16x16x32_bf16(a_h, b1h, acc1, 0, 0, 0);
                acc0 = __builtin_amdgcn_mfma_f32_16x16x32_bf16(a_h, b0l, acc0, 0, 0, 0);
                acc1 = __builtin_amdgcn_mfma_f32_16x16x32_bf16(a_h, b1l, acc1, 0, 0, 0);
                acc0 = __builtin_amdgcn_mfma_f32_16x16x32_bf16(a_l, b0h, acc0, 0, 0, 0);
                acc1 = __builtin_amdgcn_mfma_f32_16x16x32_bf16(a_l, b1h, acc1, 0, 0, 0);
            }
        }

        __syncthreads();
        float* sG = (float*)sA;  // 6 gate planes [16 x 32] fp32 (12 KB, aliases sA)
        {
            // C/D layout: col = lane&15, row = (lane>>4)*4 + reg  [m89/m91 verified]
#pragma unroll
            for (int r = 0; r < 4; ++r) {
                int mrow = q * 4 + r;
                sG[g * 512 + mrow * 32 + m0]      = acc0[r];
                sG[g * 512 + mrow * 32 + m0 + 16] = acc1[r];
            }
        }
        __syncthreads();

        for (int e = tid; e < 512; e += 384) {
            int mloc = e >> 5;
            int nloc = e & 31;
            int b = bbase + mloc;
            int i = ibase0 + nloc;
            float xz = sG[e], xr = sG[512 + e], xh = sG[1024 + e];
            float hz = sG[1536 + e], hr = sG[2048 + e], hh = sG[2560 + e];
            float zlin = xz + sBias[nloc]      + hz + sBias[96 + nloc];
            float rlin = xr + sBias[32 + nloc] + hr + sBias[128 + nloc];
            float xht  = xh + sBias[64 + nloc];
            float hht  = hh + sBias[160 + nloc];   // recurrent bias INSIDE r*(...) (reset_after)
            float z  = 1.0f / (1.0f + expf(-zlin));
            float r  = 1.0f / (1.0f + expf(-rlin));
            float hc = tanhf(xht + r * hht);
            size_t hidx = (size_t)b * H + i;
            float hold = same_xh ? sHold[e]
                                 : (bits2f(curhi[hidx]) + bits2f(curlo[hidx]));
            float hnew = z * hold + (1.0f - z) * hc;
            sHold[e] = hnew;
            unsigned short nh, nl;
            split_bf(hnew, nh, nl);
            dsthi[hidx] = nh;
            dstlo[hidx] = nl;
            size_t o1 = (size_t)b * (TSTEPS * H) + (size_t)t * H + i;
            if (isbf) {
                outb[o1] = __float2bfloat16(hnew);
                if (t == TSTEPS - 1) outb[(size_t)BATCH * TSTEPS * H + hidx] = __float2bfloat16(hnew);
            } else {
                outf[o1] = hnew;
                if (t == TSTEPS - 1) outf[(size_t)BATCH * TSTEPS * H + hidx] = hnew;
            }
        }

        grid.sync();   // h' visible to all XCDs; also block-level barrier for sA reuse
    }
}

extern "C" void kernel_launch(void* const* d_in, const int* in_sizes, int n_in,
                              void* d_out, int out_size, void* d_ws, size_t ws_size,
                              hipStream_t stream) {
    const void* cin  = d_in[0];
    const void* hs   = d_in[1];
    const void* Kw   = d_in[2];
    const void* Rw   = d_in[3];
    const void* bias = d_in[4];

    char* ws = (char*)d_ws;
    int* flag = (int*)ws;
    __hip_bfloat16* pwh = (__hip_bfloat16*)(ws + PW_OFF);
    __hip_bfloat16* pwl = (__hip_bfloat16*)(ws + PWL_OFF);
    unsigned short* xhi  = (unsigned short*)(ws + XHI_OFF);
    unsigned short* xlo  = (unsigned short*)(ws + XLO_OFF);
    unsigned short* h0hi = (unsigned short*)(ws + H0HI_OFF);
    unsigned short* h0lo = (unsigned short*)(ws + H0LO_OFF);
    unsigned short* h1hi = (unsigned short*)(ws + H1HI_OFF);
    unsigned short* h1lo = (unsigned short*)(ws + H1LO_OFF);

    detect_dtype<<<1, 256, 0, stream>>>((const unsigned int*)Kw, flag);
    pack_w<<<3072, 256, 0, stream>>>(Kw, Rw, pwh, pwl, flag);
    init_bufs<<<512, 256, 0, stream>>>(cin, hs, xhi, xlo, h0hi, h0lo, flag);

    const unsigned short* xhi_c = xhi;
    const unsigned short* xlo_c = xlo;
    const __hip_bfloat16* pwh_c = pwh;
    const __hip_bfloat16* pwl_c = pwl;
    const int* flag_c = flag;
    void* kargs[] = {
        (void*)&xhi_c, (void*)&xlo_c,
        (void*)&h0hi, (void*)&h0lo, (void*)&h1hi, (void*)&h1lo,
        (void*)&pwh_c, (void*)&pwl_c,
        (void*)&bias, (void*)&d_out, (void*)&flag_c
    };
    hipLaunchCooperativeKernel((void*)gru_persistent, dim3(256), dim3(384),
                               kargs, 0, stream);
}

// Round 2
// 6442.361 us; speedup vs baseline: 1.7807x; 1.7807x over previous
//
#include <hip/hip_runtime.h>
#include <hip/hip_bf16.h>

#define H 1024
#define B3H 3072
#define BATCH 128
#define TSTEPS 256
#define LROW 520                 // 512 k-chunk + 8 pad (shorts)
#define PLANE (16 * LROW)        // one 16-row bf16 plane per chunk
#define NBLK 256

typedef __attribute__((ext_vector_type(8))) short short8;
typedef __attribute__((ext_vector_type(4))) float f32x4;

static __device__ __forceinline__ float bf2f(__hip_bfloat16 v) { return __bfloat162float(v); }
static __device__ __forceinline__ unsigned short f2bf_bits(float f) {
    __hip_bfloat16 h = __float2bfloat16(f);
    return __builtin_bit_cast(unsigned short, h);
}
static __device__ __forceinline__ float bits2f(unsigned short b) {
    return bf2f(__builtin_bit_cast(__hip_bfloat16, b));
}
static __device__ __forceinline__ unsigned short bfbits(__hip_bfloat16 v) {
    return __builtin_bit_cast(unsigned short, v);
}
static __device__ __forceinline__ void split_bf(float v, unsigned short& hi, unsigned short& lo) {
    hi = f2bf_bits(v);
    lo = f2bf_bits(v - bits2f(hi));
}

// ws layout
#define BAR_OFF  128
#define PW_OFF   256
#define PWL_OFF  (PW_OFF + 12582912)
#define XHI_OFF  (PWL_OFF + 12582912)
#define XLO_OFF  (XHI_OFF + 262144)
#define H0HI_OFF (XLO_OFF + 262144)
#define H0LO_OFF (H0HI_OFF + 262144)
#define H1HI_OFF (H0LO_OFF + 262144)
#define H1LO_OFF (H1HI_OFF + 262144)

__global__ void detect_dtype(const unsigned int* __restrict__ w, int* __restrict__ flag) {
    __shared__ int cnt[256];
    int c = 0;
    for (int i = threadIdx.x; i < 4096; i += 256) {
        unsigned int v = (w[i] >> 8) & 0x7f;
        c += (v >= 0x33 && v <= 0x3f) ? 1 : 0;
    }
    cnt[threadIdx.x] = c;
    __syncthreads();
    for (int s = 128; s > 0; s >>= 1) {
        if (threadIdx.x < s) cnt[threadIdx.x] += cnt[threadIdx.x + s];
        __syncthreads();
    }
    if (threadIdx.x == 0) *flag = (cnt[0] * 2 > 4096) ? 1 : 0;
}

// Pack W into MFMA B-fragment layout, bf16 hi/lo pair (unchanged — verified).
__global__ void pack_w(const void* __restrict__ Kp, const void* __restrict__ Rp,
                       __hip_bfloat16* __restrict__ pwh, __hip_bfloat16* __restrict__ pwl,
                       const int* __restrict__ flag) {
    int idx = blockIdx.x * 256 + threadIdx.x;
    int lane = idx & 63;
    int kc   = (idx >> 6) & 31;
    int ns   = (idx >> 11) & 1;
    int it   = (idx >> 12) & 31;
    int g    = idx >> 17;
    if (g >= 6) return;
    const int isbf = *flag;
    int col   = (g % 3) * 1024 + it * 32 + ns * 16 + (lane & 15);
    int kbase = kc * 32 + (lane >> 4) * 8;
    unsigned short eh[8], el[8];
    if (isbf) {
        const __hip_bfloat16* src = (const __hip_bfloat16*)((g < 3) ? Kp : Rp);
#pragma unroll
        for (int j = 0; j < 8; ++j) { eh[j] = bfbits(src[(size_t)(kbase + j) * B3H + col]); el[j] = 0; }
    } else {
        const float* src = (const float*)((g < 3) ? Kp : Rp);
#pragma unroll
        for (int j = 0; j < 8; ++j) split_bf(src[(size_t)(kbase + j) * B3H + col], eh[j], el[j]);
    }
    uint4 vh, vl;
    vh.x = (unsigned int)eh[0] | ((unsigned int)eh[1] << 16);
    vh.y = (unsigned int)eh[2] | ((unsigned int)eh[3] << 16);
    vh.z = (unsigned int)eh[4] | ((unsigned int)eh[5] << 16);
    vh.w = (unsigned int)eh[6] | ((unsigned int)eh[7] << 16);
    vl.x = (unsigned int)el[0] | ((unsigned int)el[1] << 16);
    vl.y = (unsigned int)el[2] | ((unsigned int)el[3] << 16);
    vl.z = (unsigned int)el[4] | ((unsigned int)el[5] << 16);
    vl.w = (unsigned int)el[6] | ((unsigned int)el[7] << 16);
    *(uint4*)(pwh + (size_t)idx * 8) = vh;
    *(uint4*)(pwl + (size_t)idx * 8) = vl;
}

// Inputs -> pre-split bf16 hi/lo planes. Also zeroes the step-barrier counter.
__global__ void init_bufs(const void* __restrict__ cin, const void* __restrict__ hs,
                          unsigned short* __restrict__ xhi, unsigned short* __restrict__ xlo,
                          unsigned short* __restrict__ hhi, unsigned short* __restrict__ hlo,
                          unsigned int* __restrict__ bar,
                          const int* __restrict__ flag) {
    int i = blockIdx.x * 256 + threadIdx.x;
    if (i == 0) *bar = 0;
    if (i >= BATCH * H) return;
    float xv, hv;
    if (*flag) {
        xv = bf2f(((const __hip_bfloat16*)cin)[i]);
        hv = bf2f(((const __hip_bfloat16*)hs)[i]);
    } else {
        xv = ((const float*)cin)[i];
        hv = ((const float*)hs)[i];
    }
    unsigned short a, b;
    split_bf(xv, a, b); xhi[i] = a; xlo[i] = b;
    split_bf(hv, a, b); hhi[i] = a; hlo[i] = b;
}

// ---------------------------------------------------------------------------
// Persistent GRU, hand-rolled step barrier (NO grid.sync — its L2
// wbinv/invalidate was the R1 regression: weights re-fetched every step).
//   - Weights: normal cached loads -> stay L2-hot for all 256 steps.
//   - h planes: device-scope relaxed atomics (sc1) -> IF$ coherence point,
//     never touching (stale or hot) L2 lines.
//   - Barrier: drain own stores (vmcnt0) -> syncthreads -> tid0 fetch_add ->
//     spin on relaxed load -> syncthreads. No fences, no cache maintenance.
// Cooperative launch retained ONLY for the co-residency guarantee.
// ---------------------------------------------------------------------------
__launch_bounds__(384, 1)
__global__ void gru_persistent(const unsigned short* __restrict__ xhi,
                               const unsigned short* __restrict__ xlo,
                               unsigned short* __restrict__ h0hi,
                               unsigned short* __restrict__ h0lo,
                               unsigned short* __restrict__ h1hi,
                               unsigned short* __restrict__ h1lo,
                               const __hip_bfloat16* __restrict__ pwh,
                               const __hip_bfloat16* __restrict__ pwl,
                               const void* __restrict__ bias,
                               void* __restrict__ out,
                               unsigned int* __restrict__ bar,
                               const int* __restrict__ flag) {
    // t=0 planes: [Ahi][Alo][Bhi][Blo] per chunk; t>=1: [c0hi][c0lo][c1hi][c1lo]
    __shared__ unsigned short sA[4 * PLANE];  // 66560 B (aliased as sG fp32 post-GEMM)
    __shared__ float sHold[512];              // this block's h tile, full f32
    __shared__ float sBias[192];              // 6 gates x 32 cols

    const int tid  = threadIdx.x;
    const int g    = tid >> 6;        // gate wave 0..5
    const int lane = tid & 63;
    const int bt = blockIdx.x >> 5;   // 0..7, 16-row tiles
    const int it = blockIdx.x & 31;   // 0..31, 32-col slices
    const int bbase = bt * 16;
    const int m0 = lane & 15;
    const int q  = lane >> 4;
    const int ibase0 = it * 32;
    const int isbf = *flag;

    // preload bias once
    {
        const __hip_bfloat16* bias_b = (const __hip_bfloat16*)bias;
        const float* bias_f = (const float*)bias;
        for (int e = tid; e < 192; e += 384) {
            int gg = e >> 5;
            int i  = ibase0 + (e & 31);
            int src = (gg < 3) ? (gg * 1024 + i) : (B3H + (gg - 3) * 1024 + i);
            sBias[e] = isbf ? bf2f(bias_b[src]) : bias_f[src];
        }
    }

    const size_t boff0 = ((size_t)((g * 32 + it) * 2 + 0) * 32) * 64 + lane;
    const size_t boff1 = ((size_t)((g * 32 + it) * 2 + 1) * 32) * 64 + lane;
    const uint4* bh0 = (const uint4*)pwh + boff0;
    const uint4* bh1 = (const uint4*)pwh + boff1;
    const uint4* bl0 = (const uint4*)pwl + boff0;
    const uint4* bl1 = (const uint4*)pwl + boff1;

    __hip_bfloat16* outb = (__hip_bfloat16*)out;
    float* outf = (float*)out;

    for (int t = 0; t < TSTEPS; ++t) {
        const int cur = t & 1;
        const unsigned short* curhi = cur ? h1hi : h0hi;
        const unsigned short* curlo = cur ? h1lo : h0lo;
        unsigned short* dsthi = cur ? h0hi : h1hi;
        unsigned short* dstlo = cur ? h0lo : h1lo;

        f32x4 acc0 = {0.f, 0.f, 0.f, 0.f};
        f32x4 acc1 = {0.f, 0.f, 0.f, 0.f};

        if (t == 0) {
            // ---- t=0: x (gates 0-2) + h0 (gates 3-5), normal cached loads ----
            const unsigned short* aH0 = sA + ((g < 3) ? 0 : 2) * PLANE;
            const unsigned short* aL0 = aH0 + PLANE;
            for (int c = 0; c < 2; ++c) {
                if (c) __syncthreads();
                const int kstart = c * 512;
                for (int g4 = tid; g4 < 4096; g4 += 384) {
                    int plane = g4 >> 10;
                    int rem   = g4 & 1023;
                    int row   = rem >> 6;
                    int kg    = rem & 63;
                    const unsigned short* src =
                        (plane == 0) ? xhi : (plane == 1) ? xlo : (plane == 2) ? curhi : curlo;
                    uint4 v = *(const uint4*)&src[(size_t)(bbase + row) * H + kstart + kg * 8];
                    *(uint4*)&sA[plane * PLANE + row * LROW + kg * 8] = v;
                }
                __syncthreads();
#pragma unroll 4
                for (int kc = 0; kc < 16; ++kc) {
                    const int kcg = c * 16 + kc;
                    short8 b0h = __builtin_bit_cast(short8, bh0[(size_t)kcg * 64]);
                    short8 b1h = __builtin_bit_cast(short8, bh1[(size_t)kcg * 64]);
                    short8 b0l = __builtin_bit_cast(short8, bl0[(size_t)kcg * 64]);
                    short8 b1l = __builtin_bit_cast(short8, bl1[(size_t)kcg * 64]);
                    const int koff = kc * 32 + q * 8;
                    short8 a_h = *(const short8*)&aH0[m0 * LROW + koff];
                    short8 a_l = *(const short8*)&aL0[m0 * LROW + koff];
                    acc0 = __builtin_amdgcn_mfma_f32_16x16x32_bf16(a_h, b0h, acc0, 0, 0, 0);
                    acc1 = __builtin_amdgcn_mfma_f32_16x16x32_bf16(a_h, b1h, acc1, 0, 0, 0);
                    acc0 = __builtin_amdgcn_mfma_f32_16x16x32_bf16(a_h, b0l, acc0, 0, 0, 0);
                    acc1 = __builtin_amdgcn_mfma_f32_16x16x32_bf16(a_h, b1l, acc1, 0, 0, 0);
                    acc0 = __builtin_amdgcn_mfma_f32_16x16x32_bf16(a_l, b0h, acc0, 0, 0, 0);
                    acc1 = __builtin_amdgcn_mfma_f32_16x16x32_bf16(a_l, b1h, acc1, 0, 0, 0);
                }
            }
        } else {
            // ---- t>=1: stage BOTH chunks of h via device-scope (sc1) loads ----
            // planes: 0=c0hi 1=c0lo 2=c1hi 3=c1lo; granule = u64 (4 shorts)
            for (int g4 = tid; g4 < 8192; g4 += 384) {
                int plane = g4 >> 11;
                int rem   = g4 & 2047;
                int row   = rem >> 7;
                int kg    = rem & 127;
                int chunk = plane >> 1;
                const unsigned short* src = (plane & 1) ? curlo : curhi;
                const unsigned long long* p =
                    (const unsigned long long*)&src[(size_t)(bbase + row) * H + chunk * 512 + kg * 4];
                unsigned long long v =
                    __hip_atomic_load(p, __ATOMIC_RELAXED, __HIP_MEMORY_SCOPE_AGENT);
                *(unsigned long long*)&sA[plane * PLANE + row * LROW + kg * 4] = v;
            }
            __syncthreads();
#pragma unroll
            for (int half = 0; half < 2; ++half) {
                const unsigned short* aH = sA + (half * 2) * PLANE;
                const unsigned short* aL = aH + PLANE;
#pragma unroll 4
                for (int kc = 0; kc < 16; ++kc) {
                    const int kcg = half * 16 + kc;
                    short8 b0h = __builtin_bit_cast(short8, bh0[(size_t)kcg * 64]);
                    short8 b1h = __builtin_bit_cast(short8, bh1[(size_t)kcg * 64]);
                    short8 b0l = __builtin_bit_cast(short8, bl0[(size_t)kcg * 64]);
                    short8 b1l = __builtin_bit_cast(short8, bl1[(size_t)kcg * 64]);
                    const int koff = kc * 32 + q * 8;
                    short8 a_h = *(const short8*)&aH[m0 * LROW + koff];
                    short8 a_l = *(const short8*)&aL[m0 * LROW + koff];
                    acc0 = __builtin_amdgcn_mfma_f32_16x16x32_bf16(a_h, b0h, acc0, 0, 0, 0);
                    acc1 = __builtin_amdgcn_mfma_f32_16x16x32_bf16(a_h, b1h, acc1, 0, 0, 0);
                    acc0 = __builtin_amdgcn_mfma_f32_16x16x32_bf16(a_h, b0l, acc0, 0, 0, 0);
                    acc1 = __builtin_amdgcn_mfma_f32_16x16x32_bf16(a_h, b1l, acc1, 0, 0, 0);
                    acc0 = __builtin_amdgcn_mfma_f32_16x16x32_bf16(a_l, b0h, acc0, 0, 0, 0);
                    acc1 = __builtin_amdgcn_mfma_f32_16x16x32_bf16(a_l, b1h, acc1, 0, 0, 0);
                }
            }
        }

        __syncthreads();
        float* sG = (float*)sA;  // 6 gate planes [16 x 32] fp32 (12 KB, aliases sA)
        {
            // C/D layout: col = lane&15, row = (lane>>4)*4 + reg  [m89/m91 verified]
#pragma unroll
            for (int r = 0; r < 4; ++r) {
                int mrow = q * 4 + r;
                sG[g * 512 + mrow * 32 + m0]      = acc0[r];
                sG[g * 512 + mrow * 32 + m0 + 16] = acc1[r];
            }
        }
        __syncthreads();

        // epilogue: 256 threads x 2 adjacent elements (packed u32 h' stores)
        if (tid < 256) {
            const int e0   = tid * 2;
            const int mloc = e0 >> 5;
            const int b    = bbase + mloc;
            const int i0   = ibase0 + (e0 & 31);
            const size_t hidx0 = (size_t)b * H + i0;
            float hn[2];
            unsigned short nh[2], nl[2];
#pragma unroll
            for (int j = 0; j < 2; ++j) {
                const int e = e0 + j;
                const int nloc = e & 31;
                float xz = sG[e], xr = sG[512 + e], xh = sG[1024 + e];
                float hz = sG[1536 + e], hr = sG[2048 + e], hh = sG[2560 + e];
                float zlin = xz + sBias[nloc]      + hz + sBias[96 + nloc];
                float rlin = xr + sBias[32 + nloc] + hr + sBias[128 + nloc];
                float xht  = xh + sBias[64 + nloc];
                float hht  = hh + sBias[160 + nloc];   // recurrent bias INSIDE r*(...)
                float z  = 1.0f / (1.0f + expf(-zlin));
                float r  = 1.0f / (1.0f + expf(-rlin));
                float hc = tanhf(xht + r * hht);
                float hold = t ? sHold[e]
                               : (bits2f(curhi[hidx0 + j]) + bits2f(curlo[hidx0 + j]));
                float hnew = z * hold + (1.0f - z) * hc;
                sHold[e] = hnew;
                hn[j] = hnew;
                split_bf(hnew, nh[j], nl[j]);
            }
            if (t < TSTEPS - 1) {
                unsigned int hiw = (unsigned int)nh[0] | ((unsigned int)nh[1] << 16);
                unsigned int low = (unsigned int)nl[0] | ((unsigned int)nl[1] << 16);
                __hip_atomic_store((unsigned int*)&dsthi[hidx0], hiw,
                                   __ATOMIC_RELAXED, __HIP_MEMORY_SCOPE_AGENT);
                __hip_atomic_store((unsigned int*)&dstlo[hidx0], low,
                                   __ATOMIC_RELAXED, __HIP_MEMORY_SCOPE_AGENT);
            }
            const size_t o1 = (size_t)b * (TSTEPS * H) + (size_t)t * H + i0;
            if (isbf) {
                outb[o1]     = __float2bfloat16(hn[0]);
                outb[o1 + 1] = __float2bfloat16(hn[1]);
                if (t == TSTEPS - 1) {
                    outb[(size_t)BATCH * TSTEPS * H + hidx0]     = __float2bfloat16(hn[0]);
                    outb[(size_t)BATCH * TSTEPS * H + hidx0 + 1] = __float2bfloat16(hn[1]);
                }
            } else {
                outf[o1]     = hn[0];
                outf[o1 + 1] = hn[1];
                if (t == TSTEPS - 1) {
                    outf[(size_t)BATCH * TSTEPS * H + hidx0]     = hn[0];
                    outf[(size_t)BATCH * TSTEPS * H + hidx0 + 1] = hn[1];
                }
            }
        }

        // ---- step barrier (skip after last step) ----
        if (t < TSTEPS - 1) {
            asm volatile("s_waitcnt vmcnt(0)" ::: "memory");  // own h' stores acked at IF$
            __syncthreads();
            if (tid == 0) {
                __hip_atomic_fetch_add(bar, 1u, __ATOMIC_RELAXED, __HIP_MEMORY_SCOPE_AGENT);
                const unsigned int target = (unsigned int)NBLK * (unsigned int)(t + 1);
                while (__hip_atomic_load(bar, __ATOMIC_RELAXED, __HIP_MEMORY_SCOPE_AGENT) < target) {
                    __builtin_amdgcn_s_sleep(2);
                }
            }
            __syncthreads();
        }
    }
}

extern "C" void kernel_launch(void* const* d_in, const int* in_sizes, int n_in,
                              void* d_out, int out_size, void* d_ws, size_t ws_size,
                              hipStream_t stream) {
    const void* cin  = d_in[0];
    const void* hs   = d_in[1];
    const void* Kw   = d_in[2];
    const void* Rw   = d_in[3];
    const void* bias = d_in[4];

    char* ws = (char*)d_ws;
    int* flag = (int*)ws;
    unsigned int* bar = (unsigned int*)(ws + BAR_OFF);
    __hip_bfloat16* pwh = (__hip_bfloat16*)(ws + PW_OFF);
    __hip_bfloat16* pwl = (__hip_bfloat16*)(ws + PWL_OFF);
    unsigned short* xhi  = (unsigned short*)(ws + XHI_OFF);
    unsigned short* xlo  = (unsigned short*)(ws + XLO_OFF);
    unsigned short* h0hi = (unsigned short*)(ws + H0HI_OFF);
    unsigned short* h0lo = (unsigned short*)(ws + H0LO_OFF);
    unsigned short* h1hi = (unsigned short*)(ws + H1HI_OFF);
    unsigned short* h1lo = (unsigned short*)(ws + H1LO_OFF);

    detect_dtype<<<1, 256, 0, stream>>>((const unsigned int*)Kw, flag);
    pack_w<<<3072, 256, 0, stream>>>(Kw, Rw, pwh, pwl, flag);
    init_bufs<<<512, 256, 0, stream>>>(cin, hs, xhi, xlo, h0hi, h0lo, bar, flag);

    const unsigned short* xhi_c = xhi;
    const unsigned short* xlo_c = xlo;
    const __hip_bfloat16* pwh_c = pwh;
    const __hip_bfloat16* pwl_c = pwl;
    const int* flag_c = flag;
    void* kargs[] = {
        (void*)&xhi_c, (void*)&xlo_c,
        (void*)&h0hi, (void*)&h0lo, (void*)&h1hi, (void*)&h1lo,
        (void*)&pwh_c, (void*)&pwl_c,
        (void*)&bias, (void*)&d_out, (void*)&bar, (void*)&flag_c
    };
    hipLaunchCooperativeKernel((void*)gru_persistent, dim3(256), dim3(384),
                               kargs, 0, stream);
}